// Round 8
// baseline (473.165 us; speedup 1.0000x reference)
//
#include <hip/hip_runtime.h>

#define DIM 128
#define NCLS 40
#define SCAN_B 1024

typedef unsigned short ushort_t;
typedef __attribute__((ext_vector_type(8))) short bf16x8;
typedef __attribute__((ext_vector_type(4))) float f32x4;

__device__ __forceinline__ ushort_t f2b(float f) {
    union { float f; unsigned u; } v; v.f = f;
    unsigned r = v.u + 0x7FFFu + ((v.u >> 16) & 1u);   // round-to-nearest-even
    return (ushort_t)(r >> 16);
}

__device__ __forceinline__ float b2f(ushort_t b) {
    union { unsigned u; float f; } v; v.u = ((unsigned)b) << 16;
    return v.f;
}

// ---------------- CSR build ----------------

__global__ __launch_bounds__(256) void hist_kernel(const int* __restrict__ dst,
                                                   int* __restrict__ deg, int E) {
    int e = blockIdx.x * 256 + threadIdx.x;
    if (e < E) atomicAdd(&deg[__builtin_nontemporal_load(dst + e)], 1);
}

__global__ __launch_bounds__(256) void scan1_kernel(const int* __restrict__ deg,
                                                    int* __restrict__ bsum, int n) {
    __shared__ int sh[256];
    int base = blockIdx.x * SCAN_B;
    int s = 0;
    for (int i = threadIdx.x; i < SCAN_B; i += 256) {
        int idx = base + i;
        if (idx < n) s += deg[idx];
    }
    sh[threadIdx.x] = s;
    __syncthreads();
    for (int off = 128; off > 0; off >>= 1) {
        if (threadIdx.x < off) sh[threadIdx.x] += sh[threadIdx.x + off];
        __syncthreads();
    }
    if (threadIdx.x == 0) bsum[blockIdx.x] = sh[0];
}

__global__ __launch_bounds__(64) void scan2_kernel(int* __restrict__ bsum, int nb,
                                                   int* __restrict__ row_ptr, int n) {
    if (threadIdx.x == 0 && blockIdx.x == 0) {
        int acc = 0;
        for (int b = 0; b < nb; ++b) { int v = bsum[b]; bsum[b] = acc; acc += v; }
        row_ptr[n] = acc;   // == E
    }
}

__global__ __launch_bounds__(SCAN_B) void scan3_kernel(const int* __restrict__ deg,
                                                       const int* __restrict__ bsum,
                                                       int* __restrict__ row_ptr,
                                                       int* __restrict__ pos, int n) {
    __shared__ int sh[SCAN_B];
    int i = blockIdx.x * SCAN_B + threadIdx.x;
    int v = (i < n) ? deg[i] : 0;
    sh[threadIdx.x] = v;
    __syncthreads();
    for (int off = 1; off < SCAN_B; off <<= 1) {
        int t = (threadIdx.x >= off) ? sh[threadIdx.x - off] : 0;
        __syncthreads();
        sh[threadIdx.x] += t;
        __syncthreads();
    }
    if (i < n) {
        int rp = sh[threadIdx.x] - v + bsum[blockIdx.x];
        row_ptr[i] = rp;
        pos[i] = rp;        // fill bumps pos directly -> absolute slot
    }
}

// XCD-aligned bucketed fill: blocks with blockIdx%8==b handle dst range b.
// NT loads keep the dst/src streams from evicting the dirty eidx window in L2.
__global__ __launch_bounds__(256) void fill_kernel(const int* __restrict__ src,
                                                   const int* __restrict__ dst,
                                                   int* __restrict__ pos,
                                                   int* __restrict__ eidx,
                                                   int E, int n) {
    const int buck = blockIdx.x & 7;
    const int bsz = (n + 7) / 8;
    const int lo = buck * bsz;
    const int hi = lo + bsz;
    const int bid = blockIdx.x >> 3;
    const int nb  = gridDim.x >> 3;
    const int tid = bid * 256 + threadIdx.x;
    const int stride = nb * 256;
    for (int e = tid; e < E; e += stride) {
        int d = __builtin_nontemporal_load(dst + e);
        if (d >= lo && d < hi) {
            int p = atomicAdd(&pos[d], 1);
            eidx[p] = __builtin_nontemporal_load(src + e);
        }
    }
}

// ---------------- dtype prep ----------------

__global__ __launch_bounds__(256) void cast_kernel(const float* __restrict__ x,
                                                   ushort_t* __restrict__ xbf,
                                                   int n4) {
    int i = blockIdx.x * 256 + threadIdx.x;
    if (i >= n4) return;
    f32x4 v = __builtin_nontemporal_load(((const f32x4*)x) + i);
    ushort4 o;
    o.x = f2b(v.x); o.y = f2b(v.y); o.z = f2b(v.z); o.w = f2b(v.w);
    ((ushort4*)xbf)[i] = o;
}

// Pack W = [W1r; W1l] (256x128 fp32) into per-lane MFMA B-fragment order, bf16.
// Wp[kc*4096 + t*512 + lane*8 + j] = B[k = kc*32 + (lane>>4)*8 + j][n = t*16 + (lane&15)]
__global__ __launch_bounds__(256) void packw_kernel(const float* __restrict__ W1r,
                                                    const float* __restrict__ W1l,
                                                    ushort_t* __restrict__ Wp) {
    int o = blockIdx.x * 256 + threadIdx.x;   // 0..32767
    if (o >= 256 * DIM) return;
    int j    = o & 7;
    int lane = (o >> 3) & 63;
    int t    = (o >> 9) & 7;
    int kc   = o >> 12;
    int k = kc * 32 + (lane >> 4) * 8 + j;
    int n = t * 16 + (lane & 15);
    float v = (k < DIM) ? W1r[k * DIM + n] : W1l[(k - DIM) * DIM + n];
    Wp[o] = f2b(v);
}

// Pack W2_l (128x40 fp32) into B-fragment order, bf16, cols zero-padded to 48.
__global__ __launch_bounds__(256) void packw2_kernel(const float* __restrict__ W2l,
                                                     ushort_t* __restrict__ Wp2) {
    int o = blockIdx.x * 256 + threadIdx.x;   // 0..6143
    if (o >= 4 * 1536) return;
    int j    = o & 7;
    int lane = (o >> 3) & 63;
    int rem  = o >> 9;
    int t    = rem % 3;
    int kc   = rem / 3;
    int k  = kc * 32 + (lane >> 4) * 8 + j;
    int nn = t * 16 + (lane & 15);
    Wp2[o] = (nn < NCLS) ? f2b(W2l[k * NCLS + nn]) : (ushort_t)0;
}

// ---------------- compute ----------------

// mxbf[node] = mean over CSR neighbors of xbf[src]
__global__ __launch_bounds__(256) void gather128_kernel(
    const ushort_t* __restrict__ Ybf, const int* __restrict__ row_ptr,
    const int* __restrict__ eidx, ushort_t* __restrict__ Bbf, int n)
{
    int t = blockIdx.x * 256 + threadIdx.x;
    int node = t >> 5;
    if (node >= n) return;
    int q = t & 31;
    int j  = row_ptr[node];
    int je = row_ptr[node + 1];
    const float id = 1.0f / fmaxf((float)(je - j), 1.0f);
    float4 acc = make_float4(0.f, 0.f, 0.f, 0.f);
    for (; j + 1 < je; j += 2) {
        int s0 = __builtin_nontemporal_load(eidx + j);
        int s1 = __builtin_nontemporal_load(eidx + j + 1);
        ushort4 v0 = ((const ushort4*)(Ybf + (size_t)s0 * DIM))[q];
        ushort4 v1 = ((const ushort4*)(Ybf + (size_t)s1 * DIM))[q];
        acc.x += b2f(v0.x) + b2f(v1.x);
        acc.y += b2f(v0.y) + b2f(v1.y);
        acc.z += b2f(v0.z) + b2f(v1.z);
        acc.w += b2f(v0.w) + b2f(v1.w);
    }
    if (j < je) {
        int s0 = __builtin_nontemporal_load(eidx + j);
        ushort4 v0 = ((const ushort4*)(Ybf + (size_t)s0 * DIM))[q];
        acc.x += b2f(v0.x); acc.y += b2f(v0.y); acc.z += b2f(v0.z); acc.w += b2f(v0.w);
    }
    ushort4 o;
    o.x = f2b(acc.x * id); o.y = f2b(acc.y * id);
    o.z = f2b(acc.z * id); o.w = f2b(acc.w * id);
    ((ushort4*)(Bbf + (size_t)node * DIM))[q] = o;
}

// Fused layer-1 + layer-2-left:
//   h  = relu([xbf | mxbf] @ Wp + b1)          (K=256, 8 MFMA accums/wave)
//   Hbf = bf16(h)  (coalesced dwordx4 stores via LDS readback regs)
//   Cbf = bf16(h @ W2_l)  (per-wave LDS transpose -> 12 MFMAs vs packed Wp2)
__global__ __launch_bounds__(256) void mfma_gemm_kernel(
    const ushort_t* __restrict__ xbf, const ushort_t* __restrict__ mxbf,
    const ushort_t* __restrict__ Wp, const ushort_t* __restrict__ Wp2,
    const float* __restrict__ bias,
    ushort_t* __restrict__ Hbf, ushort_t* __restrict__ Cbf, int n)
{
    __shared__ ushort_t hl[4][16 * 136];   // 16 rows x 136 (pad 8) bf16 per wave
    const int wave = threadIdx.x >> 6;
    const int lane = threadIdx.x & 63;
    const int m16  = lane & 15;
    const int quad = lane >> 4;
    const int row0 = blockIdx.x * 64 + wave * 16;
    int arow = row0 + m16;
    if (arow >= n) arow = n - 1;          // clamp; OOB rows never stored
    f32x4 acc[8];
    #pragma unroll
    for (int t = 0; t < 8; ++t) acc[t] = (f32x4){0.f, 0.f, 0.f, 0.f};
    const ushort_t* __restrict__ xrow = xbf  + (size_t)arow * DIM;
    const ushort_t* __restrict__ mrow = mxbf + (size_t)arow * DIM;
    #pragma unroll
    for (int kc = 0; kc < 8; ++kc) {
        const int kcol = (kc & 3) * 32 + quad * 8;
        const bf16x8 afrag = *(const bf16x8*)((kc < 4 ? xrow : mrow) + kcol);
        const ushort_t* __restrict__ wp = Wp + (size_t)kc * 4096 + (size_t)lane * 8;
        #pragma unroll
        for (int t = 0; t < 8; ++t) {
            const bf16x8 bfrag = *(const bf16x8*)(wp + (size_t)t * 512);
            acc[t] = __builtin_amdgcn_mfma_f32_16x16x32_bf16(afrag, bfrag, acc[t], 0, 0, 0);
        }
    }
    // epilogue 1: relu+bias, stage h tile (bf16) into this wave's LDS region.
    ushort_t* __restrict__ hw = hl[wave];
    #pragma unroll
    for (int t = 0; t < 8; ++t) {
        const int col = t * 16 + m16;
        const float bv = bias[col];
        #pragma unroll
        for (int r = 0; r < 4; ++r) {
            hw[(quad * 4 + r) * 136 + col] = f2b(fmaxf(acc[t][r] + bv, 0.f));
        }
    }
    // second GEMM: C_tile = h_tile @ W2_l   (K=128 -> 4 chunks)
    f32x4 acc2[3];
    #pragma unroll
    for (int t = 0; t < 3; ++t) acc2[t] = (f32x4){0.f, 0.f, 0.f, 0.f};
    const bool rowok = (row0 + m16) < n;
    #pragma unroll
    for (int kc = 0; kc < 4; ++kc) {
        const bf16x8 afrag2 = *(const bf16x8*)(hw + m16 * 136 + kc * 32 + quad * 8);
        if (rowok)
            *(bf16x8*)(Hbf + (size_t)(row0 + m16) * DIM + kc * 32 + quad * 8) = afrag2;
        const ushort_t* __restrict__ wp2 = Wp2 + (size_t)kc * 1536 + (size_t)lane * 8;
        #pragma unroll
        for (int t = 0; t < 3; ++t) {
            const bf16x8 bfrag = *(const bf16x8*)(wp2 + (size_t)t * 512);
            acc2[t] = __builtin_amdgcn_mfma_f32_16x16x32_bf16(afrag2, bfrag, acc2[t], 0, 0, 0);
        }
    }
    #pragma unroll
    for (int t = 0; t < 3; ++t) {
        const int col = t * 16 + m16;
        if (col >= NCLS) continue;
        #pragma unroll
        for (int r = 0; r < 4; ++r) {
            const int row = row0 + quad * 4 + r;
            if (row < n) Cbf[(size_t)row * NCLS + col] = f2b(acc2[t][r]);
        }
    }
}

// Dg[node] = mean over CSR neighbors of Cbf[src]; 10 lanes per node (ushort4 each)
__global__ __launch_bounds__(256) void gather40_kernel(
    const ushort_t* __restrict__ Cbf, const int* __restrict__ row_ptr,
    const int* __restrict__ eidx, float* __restrict__ Dg, int n)
{
    int t = blockIdx.x * 256 + threadIdx.x;
    int node = t / 10;
    if (node >= n) return;
    int q = t - node * 10;
    int j  = row_ptr[node];
    int je = row_ptr[node + 1];
    const float id = 1.0f / fmaxf((float)(je - j), 1.0f);
    float4 acc = make_float4(0.f, 0.f, 0.f, 0.f);
    for (; j + 1 < je; j += 2) {
        int s0 = __builtin_nontemporal_load(eidx + j);
        int s1 = __builtin_nontemporal_load(eidx + j + 1);
        ushort4 v0 = ((const ushort4*)(Cbf + (size_t)s0 * NCLS))[q];
        ushort4 v1 = ((const ushort4*)(Cbf + (size_t)s1 * NCLS))[q];
        acc.x += b2f(v0.x) + b2f(v1.x);
        acc.y += b2f(v0.y) + b2f(v1.y);
        acc.z += b2f(v0.z) + b2f(v1.z);
        acc.w += b2f(v0.w) + b2f(v1.w);
    }
    if (j < je) {
        int s0 = __builtin_nontemporal_load(eidx + j);
        ushort4 v0 = ((const ushort4*)(Cbf + (size_t)s0 * NCLS))[q];
        acc.x += b2f(v0.x); acc.y += b2f(v0.y); acc.z += b2f(v0.z); acc.w += b2f(v0.w);
    }
    acc.x *= id; acc.y *= id; acc.z *= id; acc.w *= id;
    ((float4*)(Dg + (size_t)node * NCLS))[q] = acc;
}

// out = softmax(Agg + b2 + Hbf @ W2_r), one thread per node (40 logits in regs)
__global__ __launch_bounds__(256) void final_kernel(
    const ushort_t* __restrict__ Hbf, const float* __restrict__ Agg,
    const float* __restrict__ W, const float* __restrict__ b2,
    float* __restrict__ out, int n)
{
    int nd = blockIdx.x * 256 + threadIdx.x;
    if (nd >= n) return;
    float lg[NCLS];
    const float* __restrict__ ag = Agg + (size_t)nd * NCLS;
    #pragma unroll
    for (int c = 0; c < NCLS; ++c) lg[c] = ag[c] + b2[c];
    const ushort_t* __restrict__ h = Hbf + (size_t)nd * DIM;
    for (int k = 0; k < DIM; k += 4) {
        const ushort4 hu = *(const ushort4*)(h + k);
        const float hx = b2f(hu.x), hy = b2f(hu.y), hz = b2f(hu.z), hw = b2f(hu.w);
        const float* __restrict__ w0 = W + (size_t)(k + 0) * NCLS;
        const float* __restrict__ w1 = W + (size_t)(k + 1) * NCLS;
        const float* __restrict__ w2 = W + (size_t)(k + 2) * NCLS;
        const float* __restrict__ w3 = W + (size_t)(k + 3) * NCLS;
        #pragma unroll
        for (int c = 0; c < NCLS; ++c) {
            float acc = lg[c];
            acc = fmaf(hx, w0[c], acc);
            acc = fmaf(hy, w1[c], acc);
            acc = fmaf(hz, w2[c], acc);
            acc = fmaf(hw, w3[c], acc);
            lg[c] = acc;
        }
    }
    float m = lg[0];
    #pragma unroll
    for (int c = 1; c < NCLS; ++c) m = fmaxf(m, lg[c]);
    float s = 0.f;
    #pragma unroll
    for (int c = 0; c < NCLS; ++c) { lg[c] = __expf(lg[c] - m); s += lg[c]; }
    const float inv = 1.0f / s;
    float* __restrict__ o = out + (size_t)nd * NCLS;
    #pragma unroll
    for (int c = 0; c < NCLS; ++c) o[c] = lg[c] * inv;
}

extern "C" void kernel_launch(void* const* d_in, const int* in_sizes, int n_in,
                              void* d_out, int out_size, void* d_ws, size_t ws_size,
                              hipStream_t stream) {
    const float* x   = (const float*)d_in[0];
    const int*   ei  = (const int*)d_in[1];
    const float* W1l = (const float*)d_in[2];
    const float* W1r = (const float*)d_in[3];
    const float* b1  = (const float*)d_in[4];
    const float* W2l = (const float*)d_in[5];
    const float* W2r = (const float*)d_in[6];
    const float* b2  = (const float*)d_in[7];
    float* out = (float*)d_out;

    const int n = in_sizes[0] / DIM;   // 100000
    const int E = in_sizes[1] / 2;     // 1600000
    const int* src = ei;
    const int* dst = ei + E;
    const int nb = (n + SCAN_B - 1) / SCAN_B;   // 98 scan blocks

    // workspace layout:
    //   xbf (25.6MB) | mxbf (25.6MB) | Hbf (25.6MB bf16) | Cbf (8MB bf16)
    //   | Wp (64KB) | Wp2 (12KB) | eidx[E] | row_ptr[n+1] | deg[n] | pos[n] | bsum[128]
    // Dg (16MB fp32) aliases mxbf (free after mfma_gemm consumes it).
    ushort_t* xbf     = (ushort_t*)d_ws;
    ushort_t* mxbf    = xbf + (size_t)n * DIM;
    ushort_t* Hbf     = mxbf + (size_t)n * DIM;
    ushort_t* Cbf     = Hbf + (size_t)n * DIM;
    ushort_t* Wp      = Cbf + (size_t)n * NCLS;
    ushort_t* Wp2     = Wp + 256 * DIM;
    int*      eidx    = (int*)(Wp2 + 4 * 1536);
    int*      row_ptr = eidx + E;
    int*      deg     = row_ptr + (n + 1);
    int*      pos     = deg + n;
    int*      bsum    = pos + n;
    float*    Dg      = (float*)mxbf;   // reuse after mfma_gemm

    (void)hipMemsetAsync(deg, 0, (size_t)n * sizeof(int), stream);

    // --- CSR build + dtype prep ---
    hist_kernel  <<<(E + 255) / 256, 256, 0, stream>>>(dst, deg, E);
    scan1_kernel <<<nb, 256, 0, stream>>>(deg, bsum, n);
    scan2_kernel <<<1, 64, 0, stream>>>(bsum, nb, row_ptr, n);
    scan3_kernel <<<nb, SCAN_B, 0, stream>>>(deg, bsum, row_ptr, pos, n);
    fill_kernel  <<<2048, 256, 0, stream>>>(src, dst, pos, eidx, E, n);
    cast_kernel  <<<(n * 32 + 255) / 256, 256, 0, stream>>>(x, xbf, n * 32);
    packw_kernel <<<128, 256, 0, stream>>>(W1r, W1l, Wp);
    packw2_kernel<<<24, 256, 0, stream>>>(W2l, Wp2);

    // --- layer 1 + layer-2-left (fused) ---
    {
        long long t = (long long)n * 32;
        gather128_kernel<<<(int)((t + 255) / 256), 256, 0, stream>>>(xbf, row_ptr, eidx, mxbf, n);
    }
    mfma_gemm_kernel<<<(n + 63) / 64, 256, 0, stream>>>(xbf, mxbf, Wp, Wp2, b1, Hbf, Cbf, n);

    // --- layer 2 ---
    {
        long long t = (long long)n * 10;
        gather40_kernel<<<(int)((t + 255) / 256), 256, 0, stream>>>(Cbf, row_ptr, eidx, Dg, n);
    }
    final_kernel<<<(n + 255) / 256, 256, 0, stream>>>(Hbf, Dg, W2r, b2, out, n);
}

// Round 9
// 422.917 us; speedup vs baseline: 1.1188x; 1.1188x over previous
//
#include <hip/hip_runtime.h>

#define DIM 128
#define NCLS 40
#define SCAN_B 1024

typedef unsigned short ushort_t;
typedef __attribute__((ext_vector_type(8))) short bf16x8;
typedef __attribute__((ext_vector_type(4))) float f32x4;

__device__ __forceinline__ ushort_t f2b(float f) {
    union { float f; unsigned u; } v; v.f = f;
    unsigned r = v.u + 0x7FFFu + ((v.u >> 16) & 1u);   // round-to-nearest-even
    return (ushort_t)(r >> 16);
}

__device__ __forceinline__ float b2f(ushort_t b) {
    union { unsigned u; float f; } v; v.u = ((unsigned)b) << 16;
    return v.f;
}

// accumulate 4 fp8(e4m3) values packed in w into a float4
__device__ __forceinline__ void acc_fp8x4(float4& a, int w) {
    a.x += __builtin_amdgcn_cvt_f32_fp8(w, 0);
    a.y += __builtin_amdgcn_cvt_f32_fp8(w, 1);
    a.z += __builtin_amdgcn_cvt_f32_fp8(w, 2);
    a.w += __builtin_amdgcn_cvt_f32_fp8(w, 3);
}

// ---------------- CSR build ----------------

__global__ __launch_bounds__(256) void hist_kernel(const int* __restrict__ dst,
                                                   int* __restrict__ deg, int E) {
    int e = blockIdx.x * 256 + threadIdx.x;
    if (e < E) atomicAdd(&deg[__builtin_nontemporal_load(dst + e)], 1);
}

__global__ __launch_bounds__(256) void scan1_kernel(const int* __restrict__ deg,
                                                    int* __restrict__ bsum, int n) {
    __shared__ int sh[256];
    int base = blockIdx.x * SCAN_B;
    int s = 0;
    for (int i = threadIdx.x; i < SCAN_B; i += 256) {
        int idx = base + i;
        if (idx < n) s += deg[idx];
    }
    sh[threadIdx.x] = s;
    __syncthreads();
    for (int off = 128; off > 0; off >>= 1) {
        if (threadIdx.x < off) sh[threadIdx.x] += sh[threadIdx.x + off];
        __syncthreads();
    }
    if (threadIdx.x == 0) bsum[blockIdx.x] = sh[0];
}

__global__ __launch_bounds__(64) void scan2_kernel(int* __restrict__ bsum, int nb,
                                                   int* __restrict__ row_ptr, int n) {
    if (threadIdx.x == 0 && blockIdx.x == 0) {
        int acc = 0;
        for (int b = 0; b < nb; ++b) { int v = bsum[b]; bsum[b] = acc; acc += v; }
        row_ptr[n] = acc;   // == E
    }
}

__global__ __launch_bounds__(SCAN_B) void scan3_kernel(const int* __restrict__ deg,
                                                       const int* __restrict__ bsum,
                                                       int* __restrict__ row_ptr,
                                                       int* __restrict__ pos, int n) {
    __shared__ int sh[SCAN_B];
    int i = blockIdx.x * SCAN_B + threadIdx.x;
    int v = (i < n) ? deg[i] : 0;
    sh[threadIdx.x] = v;
    __syncthreads();
    for (int off = 1; off < SCAN_B; off <<= 1) {
        int t = (threadIdx.x >= off) ? sh[threadIdx.x - off] : 0;
        __syncthreads();
        sh[threadIdx.x] += t;
        __syncthreads();
    }
    if (i < n) {
        int rp = sh[threadIdx.x] - v + bsum[blockIdx.x];
        row_ptr[i] = rp;
        pos[i] = rp;        // fill bumps pos directly -> absolute slot
    }
}

// XCD-aligned bucketed fill: blocks with blockIdx%8==b handle dst range b.
// NT loads keep the dst/src streams from evicting the dirty eidx window in L2.
__global__ __launch_bounds__(256) void fill_kernel(const int* __restrict__ src,
                                                   const int* __restrict__ dst,
                                                   int* __restrict__ pos,
                                                   int* __restrict__ eidx,
                                                   int E, int n) {
    const int buck = blockIdx.x & 7;
    const int bsz = (n + 7) / 8;
    const int lo = buck * bsz;
    const int hi = lo + bsz;
    const int bid = blockIdx.x >> 3;
    const int nb  = gridDim.x >> 3;
    const int tid = bid * 256 + threadIdx.x;
    const int stride = nb * 256;
    for (int e = tid; e < E; e += stride) {
        int d = __builtin_nontemporal_load(dst + e);
        if (d >= lo && d < hi) {
            int p = atomicAdd(&pos[d], 1);
            eidx[p] = __builtin_nontemporal_load(src + e);
        }
    }
}

// ---------------- dtype prep ----------------

// xbf = bf16(x) for the MFMA root path; xq = fp8-e4m3(x) for the gather table
__global__ __launch_bounds__(256) void cast_kernel(const float* __restrict__ x,
                                                   ushort_t* __restrict__ xbf,
                                                   unsigned* __restrict__ xq,
                                                   int n4) {
    int i = blockIdx.x * 256 + threadIdx.x;
    if (i >= n4) return;
    f32x4 v = __builtin_nontemporal_load(((const f32x4*)x) + i);
    ushort4 o;
    o.x = f2b(v.x); o.y = f2b(v.y); o.z = f2b(v.z); o.w = f2b(v.w);
    ((ushort4*)xbf)[i] = o;
    int p = __builtin_amdgcn_cvt_pk_fp8_f32(v.x, v.y, 0, false);
    p = __builtin_amdgcn_cvt_pk_fp8_f32(v.z, v.w, p, true);
    xq[i] = (unsigned)p;
}

// Pack W = [W1r; W1l] (256x128 fp32) into per-lane MFMA B-fragment order, bf16.
// Wp[kc*4096 + t*512 + lane*8 + j] = B[k = kc*32 + (lane>>4)*8 + j][n = t*16 + (lane&15)]
__global__ __launch_bounds__(256) void packw_kernel(const float* __restrict__ W1r,
                                                    const float* __restrict__ W1l,
                                                    ushort_t* __restrict__ Wp) {
    int o = blockIdx.x * 256 + threadIdx.x;   // 0..32767
    if (o >= 256 * DIM) return;
    int j    = o & 7;
    int lane = (o >> 3) & 63;
    int t    = (o >> 9) & 7;
    int kc   = o >> 12;
    int k = kc * 32 + (lane >> 4) * 8 + j;
    int n = t * 16 + (lane & 15);
    float v = (k < DIM) ? W1r[k * DIM + n] : W1l[(k - DIM) * DIM + n];
    Wp[o] = f2b(v);
}

// Pack W2_l (128x40 fp32) into B-fragment order, bf16, cols zero-padded to 48.
__global__ __launch_bounds__(256) void packw2_kernel(const float* __restrict__ W2l,
                                                     ushort_t* __restrict__ Wp2) {
    int o = blockIdx.x * 256 + threadIdx.x;   // 0..6143
    if (o >= 4 * 1536) return;
    int j    = o & 7;
    int lane = (o >> 3) & 63;
    int rem  = o >> 9;
    int t    = rem % 3;
    int kc   = rem / 3;
    int k  = kc * 32 + (lane >> 4) * 8 + j;
    int nn = t * 16 + (lane & 15);
    Wp2[o] = (nn < NCLS) ? f2b(W2l[k * NCLS + nn]) : (ushort_t)0;
}

// ---------------- compute ----------------

// mxbf[node] = mean over CSR neighbors of xq[src] (fp8 in, fp32 accum, bf16 out)
// 32 lanes per node, one uint (4 fp8) per lane -> 128B/edge coalesced
__global__ __launch_bounds__(256) void gather128_kernel(
    const unsigned* __restrict__ xq, const int* __restrict__ row_ptr,
    const int* __restrict__ eidx, ushort_t* __restrict__ Bbf, int n)
{
    int t = blockIdx.x * 256 + threadIdx.x;
    int node = t >> 5;
    if (node >= n) return;
    int q = t & 31;
    int j  = row_ptr[node];
    int je = row_ptr[node + 1];
    const float id = 1.0f / fmaxf((float)(je - j), 1.0f);
    float4 acc = make_float4(0.f, 0.f, 0.f, 0.f);
    for (; j + 3 < je; j += 4) {
        int s0 = eidx[j], s1 = eidx[j + 1], s2 = eidx[j + 2], s3 = eidx[j + 3];
        int w0 = (int)xq[(size_t)s0 * 32 + q];
        int w1 = (int)xq[(size_t)s1 * 32 + q];
        int w2 = (int)xq[(size_t)s2 * 32 + q];
        int w3 = (int)xq[(size_t)s3 * 32 + q];
        acc_fp8x4(acc, w0); acc_fp8x4(acc, w1);
        acc_fp8x4(acc, w2); acc_fp8x4(acc, w3);
    }
    for (; j < je; ++j) {
        int s0 = eidx[j];
        acc_fp8x4(acc, (int)xq[(size_t)s0 * 32 + q]);
    }
    ushort4 o;
    o.x = f2b(acc.x * id); o.y = f2b(acc.y * id);
    o.z = f2b(acc.z * id); o.w = f2b(acc.w * id);
    ((ushort4*)(Bbf + (size_t)node * DIM))[q] = o;
}

// Fused layer-1 + layer-2-left:
//   h  = relu([xbf | mxbf] @ Wp + b1)          (K=256, 8 MFMA accums/wave)
//   Hbf = bf16(h)  (coalesced dwordx4 stores via LDS readback regs)
//   Cbf = bf16(h @ W2_l)  (per-wave LDS transpose -> 12 MFMAs vs packed Wp2)
__global__ __launch_bounds__(256) void mfma_gemm_kernel(
    const ushort_t* __restrict__ xbf, const ushort_t* __restrict__ mxbf,
    const ushort_t* __restrict__ Wp, const ushort_t* __restrict__ Wp2,
    const float* __restrict__ bias,
    ushort_t* __restrict__ Hbf, ushort_t* __restrict__ Cbf, int n)
{
    __shared__ ushort_t hl[4][16 * 136];   // 16 rows x 136 (pad 8) bf16 per wave
    const int wave = threadIdx.x >> 6;
    const int lane = threadIdx.x & 63;
    const int m16  = lane & 15;
    const int quad = lane >> 4;
    const int row0 = blockIdx.x * 64 + wave * 16;
    int arow = row0 + m16;
    if (arow >= n) arow = n - 1;          // clamp; OOB rows never stored
    f32x4 acc[8];
    #pragma unroll
    for (int t = 0; t < 8; ++t) acc[t] = (f32x4){0.f, 0.f, 0.f, 0.f};
    const ushort_t* __restrict__ xrow = xbf  + (size_t)arow * DIM;
    const ushort_t* __restrict__ mrow = mxbf + (size_t)arow * DIM;
    #pragma unroll
    for (int kc = 0; kc < 8; ++kc) {
        const int kcol = (kc & 3) * 32 + quad * 8;
        const bf16x8 afrag = *(const bf16x8*)((kc < 4 ? xrow : mrow) + kcol);
        const ushort_t* __restrict__ wp = Wp + (size_t)kc * 4096 + (size_t)lane * 8;
        #pragma unroll
        for (int t = 0; t < 8; ++t) {
            const bf16x8 bfrag = *(const bf16x8*)(wp + (size_t)t * 512);
            acc[t] = __builtin_amdgcn_mfma_f32_16x16x32_bf16(afrag, bfrag, acc[t], 0, 0, 0);
        }
    }
    // epilogue 1: relu+bias, stage h tile (bf16) into this wave's LDS region.
    ushort_t* __restrict__ hw = hl[wave];
    #pragma unroll
    for (int t = 0; t < 8; ++t) {
        const int col = t * 16 + m16;
        const float bv = bias[col];
        #pragma unroll
        for (int r = 0; r < 4; ++r) {
            hw[(quad * 4 + r) * 136 + col] = f2b(fmaxf(acc[t][r] + bv, 0.f));
        }
    }
    // second GEMM: C_tile = h_tile @ W2_l   (K=128 -> 4 chunks)
    f32x4 acc2[3];
    #pragma unroll
    for (int t = 0; t < 3; ++t) acc2[t] = (f32x4){0.f, 0.f, 0.f, 0.f};
    const bool rowok = (row0 + m16) < n;
    #pragma unroll
    for (int kc = 0; kc < 4; ++kc) {
        const bf16x8 afrag2 = *(const bf16x8*)(hw + m16 * 136 + kc * 32 + quad * 8);
        if (rowok)
            *(bf16x8*)(Hbf + (size_t)(row0 + m16) * DIM + kc * 32 + quad * 8) = afrag2;
        const ushort_t* __restrict__ wp2 = Wp2 + (size_t)kc * 1536 + (size_t)lane * 8;
        #pragma unroll
        for (int t = 0; t < 3; ++t) {
            const bf16x8 bfrag = *(const bf16x8*)(wp2 + (size_t)t * 512);
            acc2[t] = __builtin_amdgcn_mfma_f32_16x16x32_bf16(afrag2, bfrag, acc2[t], 0, 0, 0);
        }
    }
    #pragma unroll
    for (int t = 0; t < 3; ++t) {
        const int col = t * 16 + m16;
        if (col >= NCLS) continue;
        #pragma unroll
        for (int r = 0; r < 4; ++r) {
            const int row = row0 + quad * 4 + r;
            if (row < n) Cbf[(size_t)row * NCLS + col] = f2b(acc2[t][r]);
        }
    }
}

// Dg[node] = mean over CSR neighbors of Cbf[src]; 10 lanes per node (ushort4 each)
__global__ __launch_bounds__(256) void gather40_kernel(
    const ushort_t* __restrict__ Cbf, const int* __restrict__ row_ptr,
    const int* __restrict__ eidx, float* __restrict__ Dg, int n)
{
    int t = blockIdx.x * 256 + threadIdx.x;
    int node = t / 10;
    if (node >= n) return;
    int q = t - node * 10;
    int j  = row_ptr[node];
    int je = row_ptr[node + 1];
    const float id = 1.0f / fmaxf((float)(je - j), 1.0f);
    float4 acc = make_float4(0.f, 0.f, 0.f, 0.f);
    for (; j + 1 < je; j += 2) {
        int s0 = eidx[j], s1 = eidx[j + 1];
        ushort4 v0 = ((const ushort4*)(Cbf + (size_t)s0 * NCLS))[q];
        ushort4 v1 = ((const ushort4*)(Cbf + (size_t)s1 * NCLS))[q];
        acc.x += b2f(v0.x) + b2f(v1.x);
        acc.y += b2f(v0.y) + b2f(v1.y);
        acc.z += b2f(v0.z) + b2f(v1.z);
        acc.w += b2f(v0.w) + b2f(v1.w);
    }
    if (j < je) {
        int s0 = eidx[j];
        ushort4 v0 = ((const ushort4*)(Cbf + (size_t)s0 * NCLS))[q];
        acc.x += b2f(v0.x); acc.y += b2f(v0.y); acc.z += b2f(v0.z); acc.w += b2f(v0.w);
    }
    acc.x *= id; acc.y *= id; acc.z *= id; acc.w *= id;
    ((float4*)(Dg + (size_t)node * NCLS))[q] = acc;
}

// out = softmax(Agg + b2 + Hbf @ W2_r), one thread per node (40 logits in regs)
__global__ __launch_bounds__(256) void final_kernel(
    const ushort_t* __restrict__ Hbf, const float* __restrict__ Agg,
    const float* __restrict__ W, const float* __restrict__ b2,
    float* __restrict__ out, int n)
{
    int nd = blockIdx.x * 256 + threadIdx.x;
    if (nd >= n) return;
    float lg[NCLS];
    const float* __restrict__ ag = Agg + (size_t)nd * NCLS;
    #pragma unroll
    for (int c = 0; c < NCLS; ++c) lg[c] = ag[c] + b2[c];
    const ushort_t* __restrict__ h = Hbf + (size_t)nd * DIM;
    for (int k = 0; k < DIM; k += 4) {
        const ushort4 hu = *(const ushort4*)(h + k);
        const float hx = b2f(hu.x), hy = b2f(hu.y), hz = b2f(hu.z), hw = b2f(hu.w);
        const float* __restrict__ w0 = W + (size_t)(k + 0) * NCLS;
        const float* __restrict__ w1 = W + (size_t)(k + 1) * NCLS;
        const float* __restrict__ w2 = W + (size_t)(k + 2) * NCLS;
        const float* __restrict__ w3 = W + (size_t)(k + 3) * NCLS;
        #pragma unroll
        for (int c = 0; c < NCLS; ++c) {
            float acc = lg[c];
            acc = fmaf(hx, w0[c], acc);
            acc = fmaf(hy, w1[c], acc);
            acc = fmaf(hz, w2[c], acc);
            acc = fmaf(hw, w3[c], acc);
            lg[c] = acc;
        }
    }
    float m = lg[0];
    #pragma unroll
    for (int c = 1; c < NCLS; ++c) m = fmaxf(m, lg[c]);
    float s = 0.f;
    #pragma unroll
    for (int c = 0; c < NCLS; ++c) { lg[c] = __expf(lg[c] - m); s += lg[c]; }
    const float inv = 1.0f / s;
    float* __restrict__ o = out + (size_t)nd * NCLS;
    #pragma unroll
    for (int c = 0; c < NCLS; ++c) o[c] = lg[c] * inv;
}

extern "C" void kernel_launch(void* const* d_in, const int* in_sizes, int n_in,
                              void* d_out, int out_size, void* d_ws, size_t ws_size,
                              hipStream_t stream) {
    const float* x   = (const float*)d_in[0];
    const int*   ei  = (const int*)d_in[1];
    const float* W1l = (const float*)d_in[2];
    const float* W1r = (const float*)d_in[3];
    const float* b1  = (const float*)d_in[4];
    const float* W2l = (const float*)d_in[5];
    const float* W2r = (const float*)d_in[6];
    const float* b2  = (const float*)d_in[7];
    float* out = (float*)d_out;

    const int n = in_sizes[0] / DIM;   // 100000
    const int E = in_sizes[1] / 2;     // 1600000
    const int* src = ei;
    const int* dst = ei + E;
    const int nb = (n + SCAN_B - 1) / SCAN_B;   // 98 scan blocks

    // workspace layout (~105 MB):
    //   xbf (25.6MB) | mxbf (25.6MB) | Hbf (25.6MB) | Cbf (8MB) | xq (12.8MB fp8)
    //   | Wp (64KB) | Wp2 (12KB) | eidx[E] | row_ptr[n+1] | deg[n] | pos[n] | bsum[128]
    // Dg (16MB fp32) aliases mxbf (free after mfma_gemm consumes it).
    ushort_t* xbf     = (ushort_t*)d_ws;
    ushort_t* mxbf    = xbf + (size_t)n * DIM;
    ushort_t* Hbf     = mxbf + (size_t)n * DIM;
    ushort_t* Cbf     = Hbf + (size_t)n * DIM;
    unsigned* xq      = (unsigned*)(Cbf + (size_t)n * NCLS);
    ushort_t* Wp      = (ushort_t*)(xq + (size_t)n * 32);
    ushort_t* Wp2     = Wp + 256 * DIM;
    int*      eidx    = (int*)(Wp2 + 4 * 1536);
    int*      row_ptr = eidx + E;
    int*      deg     = row_ptr + (n + 1);
    int*      pos     = deg + n;
    int*      bsum    = pos + n;
    float*    Dg      = (float*)mxbf;   // reuse after mfma_gemm

    (void)hipMemsetAsync(deg, 0, (size_t)n * sizeof(int), stream);

    // --- CSR build + dtype prep ---
    hist_kernel  <<<(E + 255) / 256, 256, 0, stream>>>(dst, deg, E);
    scan1_kernel <<<nb, 256, 0, stream>>>(deg, bsum, n);
    scan2_kernel <<<1, 64, 0, stream>>>(bsum, nb, row_ptr, n);
    scan3_kernel <<<nb, SCAN_B, 0, stream>>>(deg, bsum, row_ptr, pos, n);
    fill_kernel  <<<2048, 256, 0, stream>>>(src, dst, pos, eidx, E, n);
    cast_kernel  <<<(n * 32 + 255) / 256, 256, 0, stream>>>(x, xbf, xq, n * 32);
    packw_kernel <<<128, 256, 0, stream>>>(W1r, W1l, Wp);
    packw2_kernel<<<24, 256, 0, stream>>>(W2l, Wp2);

    // --- layer 1 + layer-2-left (fused) ---
    {
        long long t = (long long)n * 32;
        gather128_kernel<<<(int)((t + 255) / 256), 256, 0, stream>>>(xq, row_ptr, eidx, mxbf, n);
    }
    mfma_gemm_kernel<<<(n + 63) / 64, 256, 0, stream>>>(xbf, mxbf, Wp, Wp2, b1, Hbf, Cbf, n);

    // --- layer 2 ---
    {
        long long t = (long long)n * 10;
        gather40_kernel<<<(int)((t + 255) / 256), 256, 0, stream>>>(Cbf, row_ptr, eidx, Dg, n);
    }
    final_kernel<<<(n + 255) / 256, 256, 0, stream>>>(Hbf, Dg, W2r, b2, out, n);
}

// Round 10
// 397.282 us; speedup vs baseline: 1.1910x; 1.0645x over previous
//
#include <hip/hip_runtime.h>

#define DIM 128
#define NCLS 40
#define SCAN_B 1024

typedef unsigned short ushort_t;
typedef __attribute__((ext_vector_type(8))) short bf16x8;
typedef __attribute__((ext_vector_type(4))) float f32x4;

__device__ __forceinline__ ushort_t f2b(float f) {
    union { float f; unsigned u; } v; v.f = f;
    unsigned r = v.u + 0x7FFFu + ((v.u >> 16) & 1u);   // round-to-nearest-even
    return (ushort_t)(r >> 16);
}

__device__ __forceinline__ float b2f(ushort_t b) {
    union { unsigned u; float f; } v; v.u = ((unsigned)b) << 16;
    return v.f;
}

// accumulate 4 fp8(e4m3) values packed in w into a float4
__device__ __forceinline__ void acc_fp8x4(float4& a, int w) {
    a.x += __builtin_amdgcn_cvt_f32_fp8(w, 0);
    a.y += __builtin_amdgcn_cvt_f32_fp8(w, 1);
    a.z += __builtin_amdgcn_cvt_f32_fp8(w, 2);
    a.w += __builtin_amdgcn_cvt_f32_fp8(w, 3);
}

// ---------------- fused prep: cast + packw + packw2 + deg-zero ----------------
// block ranges: [0, cb) cast | [cb, cb+128) packw | [cb+128, cb+152) packw2
//               | [cb+152, cb+152+zb) zero deg
__global__ __launch_bounds__(256) void prep_kernel(
    const float* __restrict__ x, ushort_t* __restrict__ xbf, unsigned* __restrict__ xq,
    const float* __restrict__ W1r, const float* __restrict__ W1l, ushort_t* __restrict__ Wp,
    const float* __restrict__ W2l, ushort_t* __restrict__ Wp2,
    int* __restrict__ deg, int n4, int cb, int zb, int n)
{
    const int b = blockIdx.x;
    if (b < cb) {
        int i = b * 256 + threadIdx.x;
        if (i >= n4) return;
        f32x4 v = __builtin_nontemporal_load(((const f32x4*)x) + i);
        ushort4 o;
        o.x = f2b(v.x); o.y = f2b(v.y); o.z = f2b(v.z); o.w = f2b(v.w);
        ((ushort4*)xbf)[i] = o;
        int p = __builtin_amdgcn_cvt_pk_fp8_f32(v.x, v.y, 0, false);
        p = __builtin_amdgcn_cvt_pk_fp8_f32(v.z, v.w, p, true);
        xq[i] = (unsigned)p;
    } else if (b < cb + 128) {
        int o = (b - cb) * 256 + threadIdx.x;   // 0..32767
        int j    = o & 7;
        int lane = (o >> 3) & 63;
        int t    = (o >> 9) & 7;
        int kc   = o >> 12;
        int k = kc * 32 + (lane >> 4) * 8 + j;
        int nn = t * 16 + (lane & 15);
        float v = (k < DIM) ? W1r[k * DIM + nn] : W1l[(k - DIM) * DIM + nn];
        Wp[o] = f2b(v);
    } else if (b < cb + 152) {
        int o = (b - cb - 128) * 256 + threadIdx.x;   // 0..6143
        int j    = o & 7;
        int lane = (o >> 3) & 63;
        int rem  = o >> 9;
        int t    = rem % 3;
        int kc   = rem / 3;
        int k  = kc * 32 + (lane >> 4) * 8 + j;
        int nn = t * 16 + (lane & 15);
        Wp2[o] = (nn < NCLS) ? f2b(W2l[k * NCLS + nn]) : (ushort_t)0;
    } else {
        int i = (b - cb - 152) * 256 + threadIdx.x;
        if (i < n) deg[i] = 0;
    }
}

// ---------------- CSR build ----------------

__global__ __launch_bounds__(256) void hist_kernel(const int* __restrict__ dst,
                                                   int* __restrict__ deg, int E) {
    int e = blockIdx.x * 256 + threadIdx.x;
    if (e < E) atomicAdd(&deg[__builtin_nontemporal_load(dst + e)], 1);
}

__global__ __launch_bounds__(256) void scan1_kernel(const int* __restrict__ deg,
                                                    int* __restrict__ bsum, int n) {
    __shared__ int sh[256];
    int base = blockIdx.x * SCAN_B;
    int s = 0;
    for (int i = threadIdx.x; i < SCAN_B; i += 256) {
        int idx = base + i;
        if (idx < n) s += deg[idx];
    }
    sh[threadIdx.x] = s;
    __syncthreads();
    for (int off = 128; off > 0; off >>= 1) {
        if (threadIdx.x < off) sh[threadIdx.x] += sh[threadIdx.x + off];
        __syncthreads();
    }
    if (threadIdx.x == 0) bsum[blockIdx.x] = sh[0];
}

// per-chunk exclusive scan; each block serially prefixes the (raw) bsum array
// for its offset (~98 iters, ~1us); last block writes row_ptr[n] = E.
__global__ __launch_bounds__(SCAN_B) void scan3_kernel(const int* __restrict__ deg,
                                                       const int* __restrict__ bsum,
                                                       int* __restrict__ row_ptr,
                                                       int* __restrict__ pos,
                                                       int n, int nb) {
    __shared__ int sh[SCAN_B];
    __shared__ int boff;
    int i = blockIdx.x * SCAN_B + threadIdx.x;
    int v = (i < n) ? deg[i] : 0;
    sh[threadIdx.x] = v;
    __syncthreads();
    for (int off = 1; off < SCAN_B; off <<= 1) {
        int t = (threadIdx.x >= off) ? sh[threadIdx.x - off] : 0;
        __syncthreads();
        sh[threadIdx.x] += t;
        __syncthreads();
    }
    if (threadIdx.x == 0) {
        int acc = 0;
        for (int b = 0; b < blockIdx.x; ++b) acc += bsum[b];
        boff = acc;
        if (blockIdx.x == (unsigned)(nb - 1)) {
            int tot = acc;
            for (int b = blockIdx.x; b < nb; ++b) tot += bsum[b];
            row_ptr[n] = tot;   // == E
        }
    }
    __syncthreads();
    if (i < n) {
        int rp = sh[threadIdx.x] - v + boff;
        row_ptr[i] = rp;
        pos[i] = rp;        // fill bumps pos directly -> absolute slot
    }
}

// XCD-aligned bucketed fill: blocks with blockIdx%8==b handle dst range b.
__global__ __launch_bounds__(256) void fill_kernel(const int* __restrict__ src,
                                                   const int* __restrict__ dst,
                                                   int* __restrict__ pos,
                                                   int* __restrict__ eidx,
                                                   int E, int n) {
    const int buck = blockIdx.x & 7;
    const int bsz = (n + 7) / 8;
    const int lo = buck * bsz;
    const int hi = lo + bsz;
    const int bid = blockIdx.x >> 3;
    const int nb  = gridDim.x >> 3;
    const int tid = bid * 256 + threadIdx.x;
    const int stride = nb * 256;
    for (int e = tid; e < E; e += stride) {
        int d = __builtin_nontemporal_load(dst + e);
        if (d >= lo && d < hi) {
            int p = atomicAdd(&pos[d], 1);
            eidx[p] = __builtin_nontemporal_load(src + e);
        }
    }
}

// ---------------- compute ----------------

// mxbf[node] = mean over CSR neighbors of xq[src] (fp8 in, fp32 accum, bf16 out)
__global__ __launch_bounds__(256) void gather128_kernel(
    const unsigned* __restrict__ xq, const int* __restrict__ row_ptr,
    const int* __restrict__ eidx, ushort_t* __restrict__ Bbf, int n)
{
    int t = blockIdx.x * 256 + threadIdx.x;
    int node = t >> 5;
    if (node >= n) return;
    int q = t & 31;
    int j  = row_ptr[node];
    int je = row_ptr[node + 1];
    const float id = 1.0f / fmaxf((float)(je - j), 1.0f);
    float4 acc = make_float4(0.f, 0.f, 0.f, 0.f);
    for (; j + 3 < je; j += 4) {
        int s0 = eidx[j], s1 = eidx[j + 1], s2 = eidx[j + 2], s3 = eidx[j + 3];
        int w0 = (int)xq[(size_t)s0 * 32 + q];
        int w1 = (int)xq[(size_t)s1 * 32 + q];
        int w2 = (int)xq[(size_t)s2 * 32 + q];
        int w3 = (int)xq[(size_t)s3 * 32 + q];
        acc_fp8x4(acc, w0); acc_fp8x4(acc, w1);
        acc_fp8x4(acc, w2); acc_fp8x4(acc, w3);
    }
    for (; j < je; ++j) {
        int s0 = eidx[j];
        acc_fp8x4(acc, (int)xq[(size_t)s0 * 32 + q]);
    }
    ushort4 o;
    o.x = f2b(acc.x * id); o.y = f2b(acc.y * id);
    o.z = f2b(acc.z * id); o.w = f2b(acc.w * id);
    ((ushort4*)(Bbf + (size_t)node * DIM))[q] = o;
}

// Fused layer-1 + layer-2-left:
//   h  = relu([xbf | mxbf] @ Wp + b1)          (K=256, 8 MFMA accums/wave)
//   Hbf = bf16(h)  (coalesced dwordx4 stores via LDS readback regs)
//   Cbf = bf16(h @ W2_l)  (per-wave LDS transpose -> 12 MFMAs vs packed Wp2)
__global__ __launch_bounds__(256) void mfma_gemm_kernel(
    const ushort_t* __restrict__ xbf, const ushort_t* __restrict__ mxbf,
    const ushort_t* __restrict__ Wp, const ushort_t* __restrict__ Wp2,
    const float* __restrict__ bias,
    ushort_t* __restrict__ Hbf, ushort_t* __restrict__ Cbf, int n)
{
    __shared__ ushort_t hl[4][16 * 136];   // 16 rows x 136 (pad 8) bf16 per wave
    const int wave = threadIdx.x >> 6;
    const int lane = threadIdx.x & 63;
    const int m16  = lane & 15;
    const int quad = lane >> 4;
    const int row0 = blockIdx.x * 64 + wave * 16;
    int arow = row0 + m16;
    if (arow >= n) arow = n - 1;          // clamp; OOB rows never stored
    f32x4 acc[8];
    #pragma unroll
    for (int t = 0; t < 8; ++t) acc[t] = (f32x4){0.f, 0.f, 0.f, 0.f};
    const ushort_t* __restrict__ xrow = xbf  + (size_t)arow * DIM;
    const ushort_t* __restrict__ mrow = mxbf + (size_t)arow * DIM;
    #pragma unroll
    for (int kc = 0; kc < 8; ++kc) {
        const int kcol = (kc & 3) * 32 + quad * 8;
        const bf16x8 afrag = *(const bf16x8*)((kc < 4 ? xrow : mrow) + kcol);
        const ushort_t* __restrict__ wp = Wp + (size_t)kc * 4096 + (size_t)lane * 8;
        #pragma unroll
        for (int t = 0; t < 8; ++t) {
            const bf16x8 bfrag = *(const bf16x8*)(wp + (size_t)t * 512);
            acc[t] = __builtin_amdgcn_mfma_f32_16x16x32_bf16(afrag, bfrag, acc[t], 0, 0, 0);
        }
    }
    // epilogue 1: relu+bias, stage h tile (bf16) into this wave's LDS region.
    ushort_t* __restrict__ hw = hl[wave];
    #pragma unroll
    for (int t = 0; t < 8; ++t) {
        const int col = t * 16 + m16;
        const float bv = bias[col];
        #pragma unroll
        for (int r = 0; r < 4; ++r) {
            hw[(quad * 4 + r) * 136 + col] = f2b(fmaxf(acc[t][r] + bv, 0.f));
        }
    }
    // second GEMM: C_tile = h_tile @ W2_l   (K=128 -> 4 chunks)
    f32x4 acc2[3];
    #pragma unroll
    for (int t = 0; t < 3; ++t) acc2[t] = (f32x4){0.f, 0.f, 0.f, 0.f};
    const bool rowok = (row0 + m16) < n;
    #pragma unroll
    for (int kc = 0; kc < 4; ++kc) {
        const bf16x8 afrag2 = *(const bf16x8*)(hw + m16 * 136 + kc * 32 + quad * 8);
        if (rowok)
            *(bf16x8*)(Hbf + (size_t)(row0 + m16) * DIM + kc * 32 + quad * 8) = afrag2;
        const ushort_t* __restrict__ wp2 = Wp2 + (size_t)kc * 1536 + (size_t)lane * 8;
        #pragma unroll
        for (int t = 0; t < 3; ++t) {
            const bf16x8 bfrag = *(const bf16x8*)(wp2 + (size_t)t * 512);
            acc2[t] = __builtin_amdgcn_mfma_f32_16x16x32_bf16(afrag2, bfrag, acc2[t], 0, 0, 0);
        }
    }
    #pragma unroll
    for (int t = 0; t < 3; ++t) {
        const int col = t * 16 + m16;
        if (col >= NCLS) continue;
        #pragma unroll
        for (int r = 0; r < 4; ++r) {
            const int row = row0 + quad * 4 + r;
            if (row < n) Cbf[(size_t)row * NCLS + col] = f2b(acc2[t][r]);
        }
    }
}

// Fused layer-2 gather + right-branch + softmax:
// out[nd] = softmax(mean_{s in N(nd)} Cbf[s] + b2 + Hbf[nd] @ W2_r)
// one thread per node; Cbf rows are 80B = 5 x bf16x8 (16B-aligned since 80%16==0... 80*s % 16 == 0)
__global__ __launch_bounds__(256) void final_kernel(
    const ushort_t* __restrict__ Hbf, const ushort_t* __restrict__ Cbf,
    const int* __restrict__ row_ptr, const int* __restrict__ eidx,
    const float* __restrict__ W, const float* __restrict__ b2,
    float* __restrict__ out, int n)
{
    int nd = blockIdx.x * 256 + threadIdx.x;
    if (nd >= n) return;
    int j  = row_ptr[nd];
    int je = row_ptr[nd + 1];
    const float id = 1.0f / fmaxf((float)(je - j), 1.0f);
    float lg[NCLS];
    #pragma unroll
    for (int c = 0; c < NCLS; ++c) lg[c] = 0.f;
    for (; j < je; ++j) {
        int s = eidx[j];
        const bf16x8* __restrict__ crow = (const bf16x8*)(Cbf + (size_t)s * NCLS);
        #pragma unroll
        for (int kk = 0; kk < 5; ++kk) {
            bf16x8 v = crow[kk];
            #pragma unroll
            for (int e = 0; e < 8; ++e)
                lg[kk * 8 + e] += b2f((ushort_t)v[e]);
        }
    }
    #pragma unroll
    for (int c = 0; c < NCLS; ++c) lg[c] = fmaf(lg[c], id, b2[c]);
    const ushort_t* __restrict__ h = Hbf + (size_t)nd * DIM;
    for (int k = 0; k < DIM; k += 4) {
        const ushort4 hu = *(const ushort4*)(h + k);
        const float hx = b2f(hu.x), hy = b2f(hu.y), hz = b2f(hu.z), hw = b2f(hu.w);
        const float* __restrict__ w0 = W + (size_t)(k + 0) * NCLS;   // wave-uniform -> s_load
        const float* __restrict__ w1 = W + (size_t)(k + 1) * NCLS;
        const float* __restrict__ w2 = W + (size_t)(k + 2) * NCLS;
        const float* __restrict__ w3 = W + (size_t)(k + 3) * NCLS;
        #pragma unroll
        for (int c = 0; c < NCLS; ++c) {
            float acc = lg[c];
            acc = fmaf(hx, w0[c], acc);
            acc = fmaf(hy, w1[c], acc);
            acc = fmaf(hz, w2[c], acc);
            acc = fmaf(hw, w3[c], acc);
            lg[c] = acc;
        }
    }
    float m = lg[0];
    #pragma unroll
    for (int c = 1; c < NCLS; ++c) m = fmaxf(m, lg[c]);
    float s = 0.f;
    #pragma unroll
    for (int c = 0; c < NCLS; ++c) { lg[c] = __expf(lg[c] - m); s += lg[c]; }
    const float inv = 1.0f / s;
    float* __restrict__ o = out + (size_t)nd * NCLS;
    #pragma unroll
    for (int c = 0; c < NCLS; ++c) o[c] = lg[c] * inv;
}

extern "C" void kernel_launch(void* const* d_in, const int* in_sizes, int n_in,
                              void* d_out, int out_size, void* d_ws, size_t ws_size,
                              hipStream_t stream) {
    const float* x   = (const float*)d_in[0];
    const int*   ei  = (const int*)d_in[1];
    const float* W1l = (const float*)d_in[2];
    const float* W1r = (const float*)d_in[3];
    const float* b1  = (const float*)d_in[4];
    const float* W2l = (const float*)d_in[5];
    const float* W2r = (const float*)d_in[6];
    const float* b2  = (const float*)d_in[7];
    float* out = (float*)d_out;

    const int n = in_sizes[0] / DIM;   // 100000
    const int E = in_sizes[1] / 2;     // 1600000
    const int* src = ei;
    const int* dst = ei + E;
    const int nb = (n + SCAN_B - 1) / SCAN_B;   // 98 scan blocks

    // workspace layout (~105 MB):
    //   xbf (25.6MB) | mxbf (25.6MB) | Hbf (25.6MB) | Cbf (8MB) | xq (12.8MB fp8)
    //   | Wp (64KB) | Wp2 (12KB) | eidx[E] | row_ptr[n+1] | deg[n] | pos[n] | bsum[128]
    ushort_t* xbf     = (ushort_t*)d_ws;
    ushort_t* mxbf    = xbf + (size_t)n * DIM;
    ushort_t* Hbf     = mxbf + (size_t)n * DIM;
    ushort_t* Cbf     = Hbf + (size_t)n * DIM;
    unsigned* xq      = (unsigned*)(Cbf + (size_t)n * NCLS);
    ushort_t* Wp      = (ushort_t*)(xq + (size_t)n * 32);
    ushort_t* Wp2     = Wp + 256 * DIM;
    int*      eidx    = (int*)(Wp2 + 4 * 1536);
    int*      row_ptr = eidx + E;
    int*      deg     = row_ptr + (n + 1);
    int*      pos     = deg + n;
    int*      bsum    = pos + n;

    // --- fused prep (cast + weight packs + deg zero) ---
    const int n4 = n * 32;                       // float4 items in x
    const int cb = (n4 + 255) / 256;             // cast blocks
    const int zb = (n + 255) / 256;              // deg-zero blocks
    prep_kernel<<<cb + 152 + zb, 256, 0, stream>>>(x, xbf, xq, W1r, W1l, Wp,
                                                   W2l, Wp2, deg, n4, cb, zb, n);

    // --- CSR build ---
    hist_kernel <<<(E + 255) / 256, 256, 0, stream>>>(dst, deg, E);
    scan1_kernel<<<nb, 256, 0, stream>>>(deg, bsum, n);
    scan3_kernel<<<nb, SCAN_B, 0, stream>>>(deg, bsum, row_ptr, pos, n, nb);
    fill_kernel <<<2048, 256, 0, stream>>>(src, dst, pos, eidx, E, n);

    // --- layer 1 + layer-2-left (fused) ---
    {
        long long t = (long long)n * 32;
        gather128_kernel<<<(int)((t + 255) / 256), 256, 0, stream>>>(xq, row_ptr, eidx, mxbf, n);
    }
    mfma_gemm_kernel<<<(n + 63) / 64, 256, 0, stream>>>(xbf, mxbf, Wp, Wp2, b1, Hbf, Cbf, n);

    // --- layer 2: fused gather40 + right-branch + softmax ---
    final_kernel<<<(n + 255) / 256, 256, 0, stream>>>(Hbf, Cbf, row_ptr, eidx, W2r, b2, out, n);
}